// Round 10
// baseline (132.892 us; speedup 1.0000x reference)
//
#include <hip/hip_runtime.h>

#define NN 100000
#define NE 1600000
#define ALPHA 0.2f

#define BSH   9                          // 512 nodes per bucket
#define NPBK  512                        // nodes per bucket
#define NBUCK ((NN + NPBK - 1) / NPBK)   // 196 buckets
#define NPB   512                        // partition / count blocks
#define CHUNK ((NE + NPB - 1) / NPB)     // 3125 edges per block

#define MTILES (NN / 16)                 // 6250 (NN % 16 == 0)
#define TBLKS  ((MTILES + 3) / 4)        // 1563 transform blocks

typedef __attribute__((ext_vector_type(8))) short  short8;
typedef __attribute__((ext_vector_type(4))) float  f32x4;

// ---------------- bf16 helpers (RNE pack, cheap unpack) ---------------------
__device__ __forceinline__ unsigned short f2bf(float f) {
    unsigned int u = __builtin_bit_cast(unsigned int, f);
    u += 0x7FFFu + ((u >> 16) & 1u);
    return (unsigned short)(u >> 16);
}
__device__ __forceinline__ float bf2fs(unsigned short u) {
    return __builtin_bit_cast(float, (unsigned int)u << 16);
}
__device__ __forceinline__ float bflo(unsigned int u) {
    return __builtin_bit_cast(float, u << 16);
}
__device__ __forceinline__ float bfhi(unsigned int u) {
    return __builtin_bit_cast(float, u & 0xFFFF0000u);
}

// ---------------- DPP adds (all VALU, no DS pipe) ---------------------------
template<int CTRL>
__device__ __forceinline__ float dpp_add(float x) {
    int y = __builtin_amdgcn_update_dpp(0, __builtin_bit_cast(int, x),
                                        CTRL, 0xF, 0xF, true);
    return x + __builtin_bit_cast(float, y);
}

// ---------------- 256-thread block exclusive scan ---------------------------
__device__ __forceinline__ int block_excl_scan_256(int val, int* lds4) {
    const int lane = threadIdx.x & 63;
    const int wid  = threadIdx.x >> 6;
    int incl = val;
    #pragma unroll
    for (int off = 1; off < 64; off <<= 1) {
        int t = __shfl_up(incl, off);
        if (lane >= off) incl += t;
    }
    if (lane == 63) lds4[wid] = incl;
    __syncthreads();
    int wbase = 0;
    #pragma unroll
    for (int w = 0; w < 4; w++) if (w < wid) wbase += lds4[w];
    __syncthreads();
    return wbase + incl - val;
}

// ---------------------------------------------------------------------------
// Fused K1: blocks 0..NPB-1 do the bucket histogram; blocks NPB.. do the
// MFMA node transform (split-precision bf16, fp32-equivalent).
// C/D layout (HW-verified): col = lane&15, row = (lane>>4)*4 + reg.
// ---------------------------------------------------------------------------
__global__ __launch_bounds__(256) void fused_tc_kernel(
    const float* __restrict__ nf, const float* __restrict__ Wq, const float* __restrict__ bq,
    const float* __restrict__ Wv, const float* __restrict__ bv,
    unsigned short* __restrict__ qbf, unsigned short* __restrict__ vbf,
    const int* __restrict__ etgt, int* __restrict__ hist, int* __restrict__ gtotal)
{
    __shared__ short8 sB[2][2][8][64];   // 32 KB (transform branch)
    __shared__ float  sbias[128];
    __shared__ int    h[NBUCK];          // count branch
    const int tid = threadIdx.x;

    if (blockIdx.x < NPB) {
        // ---------------- bucket histogram ----------------
        const int blk = blockIdx.x;
        for (int i = tid; i < NBUCK; i += 256) h[i] = 0;
        __syncthreads();
        const int e0 = blk * CHUNK;
        const int e1 = min(e0 + CHUNK, NE);
        for (int e = e0 + tid; e < e1; e += 256)
            atomicAdd(&h[etgt[e] >> BSH], 1);
        __syncthreads();
        for (int i = tid; i < NBUCK; i += 256) {
            int c = h[i];
            hist[blk * NBUCK + i] = c;
            if (c) atomicAdd(&gtotal[i], c);
        }
        return;
    }

    // ---------------- MFMA transform ----------------
    if (tid < 64)       sbias[tid] = bq[tid];
    else if (tid < 128) sbias[tid] = bv[tid - 64];

    for (int slot = tid; slot < 2 * 8 * 64; slot += 256) {
        const int lane  = slot & 63;
        const int ntile = (slot >> 6) & 7;
        const int kstep = slot >> 9;
        const int j     = ntile * 16 + (lane & 15);
        const int kbase = kstep * 32 + (lane >> 4) * 8;
        const float* W  = (j < 64) ? Wq : Wv;
        const int jj    = j & 63;
        short8 hi, lo;
        #pragma unroll
        for (int r = 0; r < 8; r++) {
            float w = W[(kbase + r) * 64 + jj];
            unsigned short hh = f2bf(w);
            lo[r] = (short)f2bf(w - bf2fs(hh));
            hi[r] = (short)hh;
        }
        sB[0][kstep][ntile][lane] = hi;
        sB[1][kstep][ntile][lane] = lo;
    }
    __syncthreads();

    const int lane  = tid & 63;
    const int wv_   = tid >> 6;
    const int row16 = lane & 15;
    const int kg    = lane >> 4;
    const int tb    = blockIdx.x - NPB;

    for (int wt = tb * 4 + wv_; wt < MTILES; wt += TBLKS * 4) {
        const int row = wt * 16 + row16;

        short8 ah[2], al[2];
        #pragma unroll
        for (int s = 0; s < 2; s++) {
            const float* ap = nf + (size_t)row * 64 + s * 32 + kg * 8;
            #pragma unroll
            for (int r = 0; r < 8; r++) {
                float x = ap[r];
                unsigned short hh = f2bf(x);
                al[s][r] = (short)f2bf(x - bf2fs(hh));
                ah[s][r] = (short)hh;
            }
        }

        #pragma unroll
        for (int nt = 0; nt < 8; nt++) {
            f32x4 acc = {0.f, 0.f, 0.f, 0.f};
            #pragma unroll
            for (int s = 0; s < 2; s++) {
                short8 bh = sB[0][s][nt][lane];
                short8 bl = sB[1][s][nt][lane];
                acc = __builtin_amdgcn_mfma_f32_16x16x32_bf16(ah[s], bh, acc, 0, 0, 0);
                acc = __builtin_amdgcn_mfma_f32_16x16x32_bf16(al[s], bh, acc, 0, 0, 0);
                acc = __builtin_amdgcn_mfma_f32_16x16x32_bf16(ah[s], bl, acc, 0, 0, 0);
            }
            const int col = nt * 16 + (lane & 15);
            const float b = sbias[col];
            unsigned short* outp = (col < 64) ? qbf : vbf;
            const int jj    = col & 63;
            const int rbase = wt * 16 + (lane >> 4) * 4;
            #pragma unroll
            for (int r = 0; r < 4; r++)
                outp[(size_t)(rbase + r) * 64 + jj] = f2bf(acc[r] + b);
        }
    }
}

// ---------------------------------------------------------------------------
// colbase (absorbs base_scan): every block scans gtotal (196 ints) for its
// bucket base, then scans its hist column across the NPB partition blocks
// (2 entries per thread).
// ---------------------------------------------------------------------------
__global__ __launch_bounds__(256) void colbase_kernel(
    const int* __restrict__ hist, const int* __restrict__ gtotal,
    int* __restrict__ bbase, int* __restrict__ colbase, int* __restrict__ offs)
{
    __shared__ int lds4[4];
    __shared__ int sb[256];
    const int bk = blockIdx.x;
    const int t  = threadIdx.x;

    int gval = (t < NBUCK) ? gtotal[t] : 0;
    int gex  = block_excl_scan_256(gval, lds4);
    sb[t] = gex;
    if (t == bk) bbase[bk] = gex;
    if (bk == 0 && t == NBUCK - 1) { bbase[NBUCK] = gex + gval; offs[NN] = NE; }
    __syncthreads();
    const int myBase = sb[bk];
    __syncthreads();

    int a0 = hist[(2 * t)     * NBUCK + bk];
    int a1 = hist[(2 * t + 1) * NBUCK + bk];
    int ex = block_excl_scan_256(a0 + a1, lds4);
    colbase[(2 * t)     * NBUCK + bk] = myBase + ex;
    colbase[(2 * t + 1) * NBUCK + bk] = myBase + ex + a0;
}

__global__ __launch_bounds__(256) void partition_kernel(
    const int* __restrict__ esrc, const int* __restrict__ etgt,
    const int* __restrict__ colbase, unsigned int* __restrict__ packed)
{
    __shared__ int cur[NBUCK];
    const int blk = blockIdx.x;
    for (int i = threadIdx.x; i < NBUCK; i += 256)
        cur[i] = colbase[blk * NBUCK + i];
    __syncthreads();
    const int e0 = blk * CHUNK;
    const int e1 = min(e0 + CHUNK, NE);
    for (int e = e0 + threadIdx.x; e < e1; e += 256) {
        int t = etgt[e], s = esrc[e];
        int bk = t >> BSH;
        int pos = atomicAdd(&cur[bk], 1);
        packed[pos] = (unsigned)s | ((unsigned)(t & (NPBK - 1)) << 17);
    }
}

__global__ __launch_bounds__(256) void bucket_csr_kernel(
    const unsigned int* __restrict__ packed, const int* __restrict__ bbase,
    int* __restrict__ offs, int* __restrict__ ssrc)
{
    __shared__ int cnt[NPBK];
    __shared__ int loff[NPBK];
    __shared__ int lds4[4];
    const int bk = blockIdx.x;
    const int s0 = bbase[bk], s1 = bbase[bk + 1];
    for (int i = threadIdx.x; i < NPBK; i += 256) cnt[i] = 0;
    __syncthreads();
    for (int e = s0 + threadIdx.x; e < s1; e += 256)
        atomicAdd(&cnt[packed[e] >> 17], 1);
    __syncthreads();
    int a0 = cnt[2 * threadIdx.x], a1 = cnt[2 * threadIdx.x + 1];
    int ex = block_excl_scan_256(a0 + a1, lds4);
    loff[2 * threadIdx.x]     = ex;
    loff[2 * threadIdx.x + 1] = ex + a0;
    __syncthreads();
    for (int i = threadIdx.x; i < NPBK; i += 256) {
        int node = (bk << BSH) + i;
        int g = s0 + loff[i];
        if (node < NN) offs[node] = g;
        cnt[i] = g;                      // becomes cursor
    }
    __syncthreads();
    for (int e = s0 + threadIdx.x; e < s1; e += 256) {
        unsigned p = packed[e];
        int tl  = p >> 17;
        int pos = atomicAdd(&cnt[tl], 1);
        ssrc[pos] = (int)(p & 0x1FFFFu);
    }
}

// ---------------------------------------------------------------------------
// Gather kernel v5: one wave per node; 4 edge slots; 4-stage rotating
// value/index pipeline = 16 edges (4 independent row-gathers) in flight.
// All prefetch positions clamp to end-1 (L1-hot dup). Logit:
// ak*leaky(f) = (.6ak)*f + (.4ak)*|f| with abs in fma modifiers, log2e folded.
// ---------------------------------------------------------------------------
__device__ __forceinline__ uint2 ldraw(const unsigned short* __restrict__ vb,
                                       int src, int sub) {
    return *(const uint2*)((const char*)vb + ((size_t)src << 7) + sub * 8);
}

__global__ __launch_bounds__(256) void gather_kernel(
    const unsigned short* __restrict__ qb, const unsigned short* __restrict__ vb,
    const float* __restrict__ ak,   // [16][4] row-major: ak[c*4+h]
    const int* __restrict__ offs, const int* __restrict__ ssrc,
    float* __restrict__ out)
{
    const int node = (blockIdx.x * 256 + threadIdx.x) >> 6;
    const int lane = threadIdx.x & 63;
    if (node >= NN) return;
    const int eidx = lane >> 4;      // edge slot 0..3
    const int sub  = lane & 15;
    const int h    = sub >> 2;
    const int cq   = sub & 3;

    const int start = offs[node];
    const int end   = offs[node + 1];

    if (start >= end) {
        if (lane < 16)
            *(float4*)(out + (size_t)node * 64 + sub * 4) = float4{0.f, 0.f, 0.f, 0.f};
        return;
    }
    const int end1 = end - 1;

    const float c6 = 0.6f * 1.44269504088896f;   // leaky+log2e folded
    const float c4 = 0.4f * 1.44269504088896f;
    float k0 = ak[(cq * 4 + 0) * 4 + h];
    float k1 = ak[(cq * 4 + 1) * 4 + h];
    float k2 = ak[(cq * 4 + 2) * 4 + h];
    float k3 = ak[(cq * 4 + 3) * 4 + h];
    const float a60 = c6 * k0, a40 = c4 * k0;
    const float a61 = c6 * k1, a41 = c4 * k1;
    const float a62 = c6 * k2, a42 = c4 * k2;
    const float a63 = c6 * k3, a43 = c4 * k3;

    uint2 qraw = *(const uint2*)((const char*)qb + ((size_t)node << 7) + sub * 8);
    const float q0 = bflo(qraw.x), q1 = bfhi(qraw.x);
    const float q2 = bflo(qraw.y), q3 = bfhi(qraw.y);

    // prologue: 4 independent row-gathers in flight + 4 prefetched indices
    uint2 rr[4];
    int   mi[4];
    #pragma unroll
    for (int qd = 0; qd < 4; qd++)
        rr[qd] = ldraw(vb, ssrc[min(start + 4 * qd + eidx, end1)], sub);
    #pragma unroll
    for (int qd = 0; qd < 4; qd++)
        mi[qd] = ssrc[min(start + 16 + 4 * qd + eidx, end1)];

    float a0 = 0.f, a1 = 0.f, a2 = 0.f, a3 = 0.f, ws = 0.f;

    for (int p = start; p < end; p += 16) {
        #pragma unroll
        for (int qd = 0; qd < 4; qd++) {
            float v0 = bflo(rr[qd].x), v1 = bfhi(rr[qd].x);
            float v2 = bflo(rr[qd].y), v3 = bfhi(rr[qd].y);
            rr[qd] = ldraw(vb, mi[qd], sub);               // edges p+16+4qd..
            mi[qd] = ssrc[min(p + 32 + 4 * qd + eidx, end1)];
            float f0 = q0 + v0, f1 = q1 + v1, f2 = q2 + v2, f3 = q3 + v3;
            float x;
            x = f0 * a60;          x = fmaf(fabsf(f0), a40, x);
            x = fmaf(f1, a61, x);  x = fmaf(fabsf(f1), a41, x);
            x = fmaf(f2, a62, x);  x = fmaf(fabsf(f2), a42, x);
            x = fmaf(f3, a63, x);  x = fmaf(fabsf(f3), a43, x);
            x = dpp_add<0xB1>(x);
            x = dpp_add<0x4E>(x);
            float w = (p + 4 * qd + eidx < end) ? __builtin_amdgcn_exp2f(x) : 0.f;
            ws += w;
            a0 = fmaf(w, v0, a0); a1 = fmaf(w, v1, a1);
            a2 = fmaf(w, v2, a2); a3 = fmaf(w, v3, a3);
        }
    }

    // combine the 4 edge slots (xor16 then xor32)
    a0 += __shfl_xor(a0, 16); a1 += __shfl_xor(a1, 16);
    a2 += __shfl_xor(a2, 16); a3 += __shfl_xor(a3, 16);
    ws += __shfl_xor(ws, 16);
    a0 += __shfl_xor(a0, 32); a1 += __shfl_xor(a1, 32);
    a2 += __shfl_xor(a2, 32); a3 += __shfl_xor(a3, 32);
    ws += __shfl_xor(ws, 32);

    if (lane < 16) {
        float inv = (ws > 0.f) ? __frcp_rn(ws) : 1.0f;
        float r0 = a0 * inv, r1 = a1 * inv, r2 = a2 * inv, r3 = a3 * inv;
        r0 = fmaxf(r0, ALPHA * r0); r1 = fmaxf(r1, ALPHA * r1);
        r2 = fmaxf(r2, ALPHA * r2); r3 = fmaxf(r3, ALPHA * r3);
        *(float4*)(out + (size_t)node * 64 + sub * 4) = float4{r0, r1, r2, r3};
    }
}

extern "C" void kernel_launch(void* const* d_in, const int* in_sizes, int n_in,
                              void* d_out, int out_size, void* d_ws, size_t ws_size,
                              hipStream_t stream) {
    const float* nf   = (const float*)d_in[0];
    const float* Wq   = (const float*)d_in[1];
    const float* bq   = (const float*)d_in[2];
    const float* Wv   = (const float*)d_in[3];
    const float* bv   = (const float*)d_in[4];
    const float* ak   = (const float*)d_in[5];
    const int*   esrc = (const int*)d_in[6];
    const int*   etgt = (const int*)d_in[7];
    float* out = (float*)d_out;

    // workspace layout:
    //   qbf:     NN*64      u16  (12.8 MB)
    //   vbf:     NN*64      u16  (12.8 MB)
    //   offs:    NN+1       i32
    //   ssrc:    NE         i32  (6.4 MB)
    //   packed:  NE         u32  (6.4 MB)
    //   hist:    NPB*NBUCK  i32  (401 KB)
    //   colbase: NPB*NBUCK  i32  (401 KB)
    //   gtotal:  NBUCK      i32
    //   bbase:   NBUCK+1    i32
    unsigned short* qbf     = (unsigned short*)d_ws;
    unsigned short* vbf     = qbf + (size_t)NN * 64;
    int*            offs    = (int*)(vbf + (size_t)NN * 64);
    int*            ssrc    = offs + (NN + 1);
    unsigned int*   packed  = (unsigned int*)(ssrc + NE);
    int*            hist    = (int*)(packed + NE);
    int*            colbase = hist + NPB * NBUCK;
    int*            gtotal  = colbase + NPB * NBUCK;
    int*            bbase   = gtotal + NBUCK;

    hipMemsetAsync(gtotal, 0, NBUCK * sizeof(int), stream);

    fused_tc_kernel<<<NPB + TBLKS, 256, 0, stream>>>(nf, Wq, bq, Wv, bv, qbf, vbf,
                                                     etgt, hist, gtotal);
    colbase_kernel<<<NBUCK, 256, 0, stream>>>(hist, gtotal, bbase, colbase, offs);
    partition_kernel<<<NPB, 256, 0, stream>>>(esrc, etgt, colbase, packed);
    bucket_csr_kernel<<<NBUCK, 256, 0, stream>>>(packed, bbase, offs, ssrc);
    gather_kernel<<<(NN * 64 + 255) / 256, 256, 0, stream>>>(qbf, vbf, ak, offs, ssrc, out);
}

// Round 11
// 119.621 us; speedup vs baseline: 1.1109x; 1.1109x over previous
//
#include <hip/hip_runtime.h>

#define NN 100000
#define NE 1600000
#define ALPHA 0.2f

#define BSH   9                          // 512 nodes per bucket
#define NPBK  512                        // nodes per bucket
#define NBUCK ((NN + NPBK - 1) / NPBK)   // 196 buckets
#define NPB   256                        // partition / count blocks
#define CHUNK ((NE + NPB - 1) / NPB)     // 6250 edges per block

#define MTILES (NN / 16)                 // 6250 (NN % 16 == 0)
#define TBLKS  ((MTILES + 3) / 4)        // 1563 transform blocks

typedef __attribute__((ext_vector_type(8))) short  short8;
typedef __attribute__((ext_vector_type(4))) float  f32x4;

// ---------------- bf16 helpers (RNE pack, cheap unpack) ---------------------
__device__ __forceinline__ unsigned short f2bf(float f) {
    unsigned int u = __builtin_bit_cast(unsigned int, f);
    u += 0x7FFFu + ((u >> 16) & 1u);
    return (unsigned short)(u >> 16);
}
__device__ __forceinline__ float bf2fs(unsigned short u) {
    return __builtin_bit_cast(float, (unsigned int)u << 16);
}
__device__ __forceinline__ float bflo(unsigned int u) {
    return __builtin_bit_cast(float, u << 16);
}
__device__ __forceinline__ float bfhi(unsigned int u) {
    return __builtin_bit_cast(float, u & 0xFFFF0000u);
}

// ---------------- DPP adds (all VALU, no DS pipe) ---------------------------
template<int CTRL>
__device__ __forceinline__ float dpp_add(float x) {
    int y = __builtin_amdgcn_update_dpp(0, __builtin_bit_cast(int, x),
                                        CTRL, 0xF, 0xF, true);
    return x + __builtin_bit_cast(float, y);
}

// ---------------- block exclusive scans -------------------------------------
__device__ __forceinline__ int block_excl_scan_256(int val, int* lds4) {
    const int lane = threadIdx.x & 63;
    const int wid  = threadIdx.x >> 6;
    int incl = val;
    #pragma unroll
    for (int off = 1; off < 64; off <<= 1) {
        int t = __shfl_up(incl, off);
        if (lane >= off) incl += t;
    }
    if (lane == 63) lds4[wid] = incl;
    __syncthreads();
    int wbase = 0;
    #pragma unroll
    for (int w = 0; w < 4; w++) if (w < wid) wbase += lds4[w];
    __syncthreads();
    return wbase + incl - val;
}

__device__ __forceinline__ int block_excl_scan_512(int val, int* lds8) {
    const int lane = threadIdx.x & 63;
    const int wid  = threadIdx.x >> 6;   // 0..7
    int incl = val;
    #pragma unroll
    for (int off = 1; off < 64; off <<= 1) {
        int t = __shfl_up(incl, off);
        if (lane >= off) incl += t;
    }
    if (lane == 63) lds8[wid] = incl;
    __syncthreads();
    int wbase = 0;
    #pragma unroll
    for (int w = 0; w < 8; w++) if (w < wid) wbase += lds8[w];
    __syncthreads();
    return wbase + incl - val;
}

// ---------------------------------------------------------------------------
// Fused K1: blocks 0..NPB-1 do the bucket histogram; blocks NPB.. do the
// MFMA node transform (split-precision bf16, fp32-equivalent).
// C/D layout (HW-verified): col = lane&15, row = (lane>>4)*4 + reg.
// ---------------------------------------------------------------------------
__global__ __launch_bounds__(256) void fused_tc_kernel(
    const float* __restrict__ nf, const float* __restrict__ Wq, const float* __restrict__ bq,
    const float* __restrict__ Wv, const float* __restrict__ bv,
    unsigned short* __restrict__ qbf, unsigned short* __restrict__ vbf,
    const int* __restrict__ etgt, int* __restrict__ hist, int* __restrict__ gtotal)
{
    __shared__ short8 sB[2][2][8][64];   // 32 KB (transform branch)
    __shared__ float  sbias[128];
    __shared__ int    h[NBUCK];          // count branch
    const int tid = threadIdx.x;

    if (blockIdx.x < NPB) {
        // ---------------- bucket histogram ----------------
        const int blk = blockIdx.x;
        for (int i = tid; i < NBUCK; i += 256) h[i] = 0;
        __syncthreads();
        const int e0 = blk * CHUNK;
        const int e1 = min(e0 + CHUNK, NE);
        for (int e = e0 + tid; e < e1; e += 256)
            atomicAdd(&h[etgt[e] >> BSH], 1);
        __syncthreads();
        for (int i = tid; i < NBUCK; i += 256) {
            int c = h[i];
            hist[blk * NBUCK + i] = c;
            if (c) atomicAdd(&gtotal[i], c);
        }
        return;
    }

    // ---------------- MFMA transform ----------------
    if (tid < 64)       sbias[tid] = bq[tid];
    else if (tid < 128) sbias[tid] = bv[tid - 64];

    for (int slot = tid; slot < 2 * 8 * 64; slot += 256) {
        const int lane  = slot & 63;
        const int ntile = (slot >> 6) & 7;
        const int kstep = slot >> 9;
        const int j     = ntile * 16 + (lane & 15);
        const int kbase = kstep * 32 + (lane >> 4) * 8;
        const float* W  = (j < 64) ? Wq : Wv;
        const int jj    = j & 63;
        short8 hi, lo;
        #pragma unroll
        for (int r = 0; r < 8; r++) {
            float w = W[(kbase + r) * 64 + jj];
            unsigned short hh = f2bf(w);
            lo[r] = (short)f2bf(w - bf2fs(hh));
            hi[r] = (short)hh;
        }
        sB[0][kstep][ntile][lane] = hi;
        sB[1][kstep][ntile][lane] = lo;
    }
    __syncthreads();

    const int lane  = tid & 63;
    const int wv_   = tid >> 6;
    const int row16 = lane & 15;
    const int kg    = lane >> 4;
    const int tb    = blockIdx.x - NPB;

    for (int wt = tb * 4 + wv_; wt < MTILES; wt += TBLKS * 4) {
        const int row = wt * 16 + row16;

        short8 ah[2], al[2];
        #pragma unroll
        for (int s = 0; s < 2; s++) {
            const float* ap = nf + (size_t)row * 64 + s * 32 + kg * 8;
            #pragma unroll
            for (int r = 0; r < 8; r++) {
                float x = ap[r];
                unsigned short hh = f2bf(x);
                al[s][r] = (short)f2bf(x - bf2fs(hh));
                ah[s][r] = (short)hh;
            }
        }

        #pragma unroll
        for (int nt = 0; nt < 8; nt++) {
            f32x4 acc = {0.f, 0.f, 0.f, 0.f};
            #pragma unroll
            for (int s = 0; s < 2; s++) {
                short8 bh = sB[0][s][nt][lane];
                short8 bl = sB[1][s][nt][lane];
                acc = __builtin_amdgcn_mfma_f32_16x16x32_bf16(ah[s], bh, acc, 0, 0, 0);
                acc = __builtin_amdgcn_mfma_f32_16x16x32_bf16(al[s], bh, acc, 0, 0, 0);
                acc = __builtin_amdgcn_mfma_f32_16x16x32_bf16(ah[s], bl, acc, 0, 0, 0);
            }
            const int col = nt * 16 + (lane & 15);
            const float b = sbias[col];
            unsigned short* outp = (col < 64) ? qbf : vbf;
            const int jj    = col & 63;
            const int rbase = wt * 16 + (lane >> 4) * 4;
            #pragma unroll
            for (int r = 0; r < 4; r++)
                outp[(size_t)(rbase + r) * 64 + jj] = f2bf(acc[r] + b);
        }
    }
}

// ---------------------------------------------------------------------------
// colbase (absorbs base_scan): every block scans gtotal (196 ints) for its
// bucket base, then scans its hist column across the NPB partition blocks.
// ---------------------------------------------------------------------------
__global__ __launch_bounds__(256) void colbase_kernel(
    const int* __restrict__ hist, const int* __restrict__ gtotal,
    int* __restrict__ bbase, int* __restrict__ colbase, int* __restrict__ offs)
{
    __shared__ int lds4[4];
    __shared__ int sb[256];
    const int bk = blockIdx.x;
    const int t  = threadIdx.x;

    int gval = (t < NBUCK) ? gtotal[t] : 0;
    int gex  = block_excl_scan_256(gval, lds4);
    sb[t] = gex;
    if (t == bk) bbase[bk] = gex;
    if (bk == 0 && t == NBUCK - 1) { bbase[NBUCK] = gex + gval; offs[NN] = NE; }
    __syncthreads();
    const int myBase = sb[bk];
    __syncthreads();

    int val = hist[t * NBUCK + bk];
    int ex  = block_excl_scan_256(val, lds4);
    colbase[t * NBUCK + bk] = myBase + ex;
}

__global__ __launch_bounds__(256) void partition_kernel(
    const int* __restrict__ esrc, const int* __restrict__ etgt,
    const int* __restrict__ colbase, unsigned int* __restrict__ packed)
{
    __shared__ int cur[NBUCK];
    const int blk = blockIdx.x;
    for (int i = threadIdx.x; i < NBUCK; i += 256)
        cur[i] = colbase[blk * NBUCK + i];
    __syncthreads();
    const int e0 = blk * CHUNK;
    const int e1 = min(e0 + CHUNK, NE);
    for (int e = e0 + threadIdx.x; e < e1; e += 256) {
        int t = etgt[e], s = esrc[e];
        int bk = t >> BSH;
        int pos = atomicAdd(&cur[bk], 1);
        packed[pos] = (unsigned)s | ((unsigned)(t & (NPBK - 1)) << 17);
    }
}

// 512 threads: 1 node-bin per thread, 8 waves/block for latency hiding
// (only NBUCK=196 blocks exist — parallelism lives inside the block).
__global__ __launch_bounds__(512) void bucket_csr_kernel(
    const unsigned int* __restrict__ packed, const int* __restrict__ bbase,
    int* __restrict__ offs, int* __restrict__ ssrc)
{
    __shared__ int cnt[NPBK];
    __shared__ int lds8[8];
    const int bk  = blockIdx.x;
    const int tid = threadIdx.x;
    const int s0 = bbase[bk], s1 = bbase[bk + 1];
    cnt[tid] = 0;
    __syncthreads();
    for (int e = s0 + tid; e < s1; e += 512)
        atomicAdd(&cnt[packed[e] >> 17], 1);
    __syncthreads();
    int a  = cnt[tid];
    int ex = block_excl_scan_512(a, lds8);
    const int node = (bk << BSH) + tid;
    const int g = s0 + ex;
    if (node < NN) offs[node] = g;
    __syncthreads();
    cnt[tid] = g;                        // becomes cursor
    __syncthreads();
    for (int e = s0 + tid; e < s1; e += 512) {
        unsigned p = packed[e];
        int pos = atomicAdd(&cnt[p >> 17], 1);
        ssrc[pos] = (int)(p & 0x1FFFFu);
    }
}

// ---------------------------------------------------------------------------
// Gather kernel v6: one wave per node; 8 lanes per edge (dwordx4 = 8 bf16
// channels per lane), 8 edge slots, 2-stage rotation (16 edges / 16 rows in
// flight per wave). Head logit reduce = ONE dpp add (lane^1).
// Prefetch positions clamp to end-1 (L1-hot dup). Logit:
// ak*leaky(f) = (.6ak)*f + (.4ak)*|f| with abs in fma modifiers, log2e folded.
// ---------------------------------------------------------------------------
__device__ __forceinline__ uint4 ldraw16(const unsigned short* __restrict__ vb,
                                         int src, int s8) {
    return *(const uint4*)((const char*)vb + ((size_t)src << 7) + s8 * 16);
}

__global__ __launch_bounds__(256) void gather_kernel(
    const unsigned short* __restrict__ qb, const unsigned short* __restrict__ vb,
    const float* __restrict__ ak,   // [16][4] row-major: ak[c*4+h]
    const int* __restrict__ offs, const int* __restrict__ ssrc,
    float* __restrict__ out)
{
    const int node = (blockIdx.x * 256 + threadIdx.x) >> 6;
    const int lane = threadIdx.x & 63;
    if (node >= NN) return;
    const int eslot = lane >> 3;     // edge slot 0..7
    const int s8    = lane & 7;      // channel octet 0..7
    const int h     = s8 >> 1;       // head 0..3

    const int start = offs[node];
    const int end   = offs[node + 1];

    if (start >= end) {
        if (lane < 8) {
            float4 z{0.f, 0.f, 0.f, 0.f};
            *(float4*)(out + (size_t)node * 64 + s8 * 8)     = z;
            *(float4*)(out + (size_t)node * 64 + s8 * 8 + 4) = z;
        }
        return;
    }
    const int end1 = end - 1;

    const float c6 = 0.6f * 1.44269504088896f;   // leaky + log2e folded
    const float c4 = 0.4f * 1.44269504088896f;
    float a6[8], a4[8];
    #pragma unroll
    for (int j = 0; j < 8; j++) {
        float k = ak[((s8 & 1) * 8 + j) * 4 + h];
        a6[j] = c6 * k;  a4[j] = c4 * k;
    }

    const uint4 qraw = *(const uint4*)((const char*)qb + ((size_t)node << 7) + s8 * 16);
    float q[8];
    q[0] = bflo(qraw.x); q[1] = bfhi(qraw.x);
    q[2] = bflo(qraw.y); q[3] = bfhi(qraw.y);
    q[4] = bflo(qraw.z); q[5] = bfhi(qraw.z);
    q[6] = bflo(qraw.w); q[7] = bfhi(qraw.w);

    // prologue: 2 row-gathers in flight + 2 prefetched indices per lane
    int i0 = ssrc[min(start +     eslot, end1)];
    int i1 = ssrc[min(start + 8 + eslot, end1)];
    uint4 rr0 = ldraw16(vb, i0, s8);
    uint4 rr1 = ldraw16(vb, i1, s8);
    int mi0 = ssrc[min(start + 16 + eslot, end1)];
    int mi1 = ssrc[min(start + 24 + eslot, end1)];

    float acc[8] = {0.f, 0.f, 0.f, 0.f, 0.f, 0.f, 0.f, 0.f};
    float ws = 0.f;

    for (int p = start; p < end; p += 16) {
        // ---- stage 0: edges p+0..p+7 ----
        {
            float v[8];
            v[0] = bflo(rr0.x); v[1] = bfhi(rr0.x);
            v[2] = bflo(rr0.y); v[3] = bfhi(rr0.y);
            v[4] = bflo(rr0.z); v[5] = bfhi(rr0.z);
            v[6] = bflo(rr0.w); v[7] = bfhi(rr0.w);
            rr0 = ldraw16(vb, mi0, s8);                    // edges p+16+eslot
            mi0 = ssrc[min(p + 32 + eslot, end1)];
            float x = 0.f;
            #pragma unroll
            for (int j = 0; j < 8; j++) {
                float f = q[j] + v[j];
                x = fmaf(f, a6[j], x);
                x = fmaf(fabsf(f), a4[j], x);
            }
            x = dpp_add<0xB1>(x);                          // lane^1: full head sum
            float w = (p + eslot < end) ? __builtin_amdgcn_exp2f(x) : 0.f;
            ws += w;
            #pragma unroll
            for (int j = 0; j < 8; j++) acc[j] = fmaf(w, v[j], acc[j]);
        }
        // ---- stage 1: edges p+8..p+15 ----
        {
            float v[8];
            v[0] = bflo(rr1.x); v[1] = bfhi(rr1.x);
            v[2] = bflo(rr1.y); v[3] = bfhi(rr1.y);
            v[4] = bflo(rr1.z); v[5] = bfhi(rr1.z);
            v[6] = bflo(rr1.w); v[7] = bfhi(rr1.w);
            rr1 = ldraw16(vb, mi1, s8);                    // edges p+24+eslot
            mi1 = ssrc[min(p + 40 + eslot, end1)];
            float x = 0.f;
            #pragma unroll
            for (int j = 0; j < 8; j++) {
                float f = q[j] + v[j];
                x = fmaf(f, a6[j], x);
                x = fmaf(fabsf(f), a4[j], x);
            }
            x = dpp_add<0xB1>(x);
            float w = (p + 8 + eslot < end) ? __builtin_amdgcn_exp2f(x) : 0.f;
            ws += w;
            #pragma unroll
            for (int j = 0; j < 8; j++) acc[j] = fmaf(w, v[j], acc[j]);
        }
    }

    // combine the 8 edge slots (xor8, xor16, xor32)
    #pragma unroll
    for (int m = 8; m <= 32; m <<= 1) {
        #pragma unroll
        for (int j = 0; j < 8; j++) acc[j] += __shfl_xor(acc[j], m);
        ws += __shfl_xor(ws, m);
    }

    if (lane < 8) {
        float inv = (ws > 0.f) ? __frcp_rn(ws) : 1.0f;
        float r[8];
        #pragma unroll
        for (int j = 0; j < 8; j++) {
            float t = acc[j] * inv;
            r[j] = fmaxf(t, ALPHA * t);
        }
        *(float4*)(out + (size_t)node * 64 + s8 * 8)     = float4{r[0], r[1], r[2], r[3]};
        *(float4*)(out + (size_t)node * 64 + s8 * 8 + 4) = float4{r[4], r[5], r[6], r[7]};
    }
}

extern "C" void kernel_launch(void* const* d_in, const int* in_sizes, int n_in,
                              void* d_out, int out_size, void* d_ws, size_t ws_size,
                              hipStream_t stream) {
    const float* nf   = (const float*)d_in[0];
    const float* Wq   = (const float*)d_in[1];
    const float* bq   = (const float*)d_in[2];
    const float* Wv   = (const float*)d_in[3];
    const float* bv   = (const float*)d_in[4];
    const float* ak   = (const float*)d_in[5];
    const int*   esrc = (const int*)d_in[6];
    const int*   etgt = (const int*)d_in[7];
    float* out = (float*)d_out;

    // workspace layout:
    //   qbf:     NN*64      u16  (12.8 MB)
    //   vbf:     NN*64      u16  (12.8 MB)
    //   offs:    NN+1       i32
    //   ssrc:    NE         i32  (6.4 MB)
    //   packed:  NE         u32  (6.4 MB)
    //   hist:    NPB*NBUCK  i32  (200 KB)
    //   colbase: NPB*NBUCK  i32  (200 KB)
    //   gtotal:  NBUCK      i32
    //   bbase:   NBUCK+1    i32
    unsigned short* qbf     = (unsigned short*)d_ws;
    unsigned short* vbf     = qbf + (size_t)NN * 64;
    int*            offs    = (int*)(vbf + (size_t)NN * 64);
    int*            ssrc    = offs + (NN + 1);
    unsigned int*   packed  = (unsigned int*)(ssrc + NE);
    int*            hist    = (int*)(packed + NE);
    int*            colbase = hist + NPB * NBUCK;
    int*            gtotal  = colbase + NPB * NBUCK;
    int*            bbase   = gtotal + NBUCK;

    hipMemsetAsync(gtotal, 0, NBUCK * sizeof(int), stream);

    fused_tc_kernel<<<NPB + TBLKS, 256, 0, stream>>>(nf, Wq, bq, Wv, bv, qbf, vbf,
                                                     etgt, hist, gtotal);
    colbase_kernel<<<NBUCK, 256, 0, stream>>>(hist, gtotal, bbase, colbase, offs);
    partition_kernel<<<NPB, 256, 0, stream>>>(esrc, etgt, colbase, packed);
    bucket_csr_kernel<<<NBUCK, 512, 0, stream>>>(packed, bbase, offs, ssrc);
    gather_kernel<<<(NN * 64 + 255) / 256, 256, 0, stream>>>(qbf, vbf, ak, offs, ssrc, out);
}

// Round 12
// 113.139 us; speedup vs baseline: 1.1746x; 1.0573x over previous
//
#include <hip/hip_runtime.h>

#define NN 100000
#define NE 1600000
#define ALPHA 0.2f

#define BSH   9                          // 512 nodes per bucket
#define NPBK  512                        // nodes per bucket
#define NBUCK ((NN + NPBK - 1) / NPBK)   // 196 buckets
#define NPB   256                        // partition / count blocks
#define CHUNK ((NE + NPB - 1) / NPB)     // 6250 edges per block

#define MTILES (NN / 16)                 // 6250 (NN % 16 == 0)
#define TBLKS  ((MTILES + 3) / 4)        // 1563 transform blocks

typedef __attribute__((ext_vector_type(8))) short  short8;
typedef __attribute__((ext_vector_type(4))) float  f32x4;

// ---------------- bf16 helpers (RNE pack, cheap unpack) ---------------------
__device__ __forceinline__ unsigned short f2bf(float f) {
    unsigned int u = __builtin_bit_cast(unsigned int, f);
    u += 0x7FFFu + ((u >> 16) & 1u);
    return (unsigned short)(u >> 16);
}
__device__ __forceinline__ float bf2fs(unsigned short u) {
    return __builtin_bit_cast(float, (unsigned int)u << 16);
}
__device__ __forceinline__ float bflo(unsigned int u) {
    return __builtin_bit_cast(float, u << 16);
}
__device__ __forceinline__ float bfhi(unsigned int u) {
    return __builtin_bit_cast(float, u & 0xFFFF0000u);
}

// ---------------- DPP adds (all VALU, no DS pipe) ---------------------------
template<int CTRL>
__device__ __forceinline__ float dpp_add(float x) {
    int y = __builtin_amdgcn_update_dpp(0, __builtin_bit_cast(int, x),
                                        CTRL, 0xF, 0xF, true);
    return x + __builtin_bit_cast(float, y);
}

// ---------------- block exclusive scans -------------------------------------
__device__ __forceinline__ int block_excl_scan_256(int val, int* lds4) {
    const int lane = threadIdx.x & 63;
    const int wid  = threadIdx.x >> 6;
    int incl = val;
    #pragma unroll
    for (int off = 1; off < 64; off <<= 1) {
        int t = __shfl_up(incl, off);
        if (lane >= off) incl += t;
    }
    if (lane == 63) lds4[wid] = incl;
    __syncthreads();
    int wbase = 0;
    #pragma unroll
    for (int w = 0; w < 4; w++) if (w < wid) wbase += lds4[w];
    __syncthreads();
    return wbase + incl - val;
}

__device__ __forceinline__ int block_excl_scan_512(int val, int* lds8) {
    const int lane = threadIdx.x & 63;
    const int wid  = threadIdx.x >> 6;   // 0..7
    int incl = val;
    #pragma unroll
    for (int off = 1; off < 64; off <<= 1) {
        int t = __shfl_up(incl, off);
        if (lane >= off) incl += t;
    }
    if (lane == 63) lds8[wid] = incl;
    __syncthreads();
    int wbase = 0;
    #pragma unroll
    for (int w = 0; w < 8; w++) if (w < wid) wbase += lds8[w];
    __syncthreads();
    return wbase + incl - val;
}

// ---------------------------------------------------------------------------
// Fused K1: blocks 0..NPB-1 do the bucket histogram; blocks NPB.. do the
// MFMA node transform.  Transform precision: acc = A_bf16 · (B_hi + B_lo)
// — B effectively full fp32 (split once per block into LDS), A bf16-rounded
// (δ≈2e-3 through the K=64 dot; negligible vs bf16 output storage).
// C/D layout (HW-verified): col = lane&15, row = (lane>>4)*4 + reg.
// ---------------------------------------------------------------------------
__global__ __launch_bounds__(256) void fused_tc_kernel(
    const float* __restrict__ nf, const float* __restrict__ Wq, const float* __restrict__ bq,
    const float* __restrict__ Wv, const float* __restrict__ bv,
    unsigned short* __restrict__ qbf, unsigned short* __restrict__ vbf,
    const int* __restrict__ etgt, int* __restrict__ hist)
{
    __shared__ short8 sB[2][2][8][64];   // [hilo][kstep][ntile][lane], 32 KB
    __shared__ float  sbias[128];
    __shared__ int    h[NBUCK];          // count branch
    const int tid = threadIdx.x;

    if (blockIdx.x < NPB) {
        // ---------------- bucket histogram ----------------
        const int blk = blockIdx.x;
        for (int i = tid; i < NBUCK; i += 256) h[i] = 0;
        __syncthreads();
        const int e0 = blk * CHUNK;
        const int e1 = min(e0 + CHUNK, NE);
        for (int e = e0 + tid; e < e1; e += 256)
            atomicAdd(&h[etgt[e] >> BSH], 1);
        __syncthreads();
        for (int i = tid; i < NBUCK; i += 256)
            hist[blk * NBUCK + i] = h[i];
        return;
    }

    // ---------------- MFMA transform ----------------
    if (tid < 64)       sbias[tid] = bq[tid];
    else if (tid < 128) sbias[tid] = bv[tid - 64];

    for (int slot = tid; slot < 2 * 8 * 64; slot += 256) {
        const int lane  = slot & 63;
        const int ntile = (slot >> 6) & 7;
        const int kstep = slot >> 9;
        const int j     = ntile * 16 + (lane & 15);
        const int kbase = kstep * 32 + (lane >> 4) * 8;
        const float* W  = (j < 64) ? Wq : Wv;
        const int jj    = j & 63;
        short8 hi, lo;
        #pragma unroll
        for (int r = 0; r < 8; r++) {
            float w = W[(kbase + r) * 64 + jj];
            unsigned short hh = f2bf(w);
            lo[r] = (short)f2bf(w - bf2fs(hh));
            hi[r] = (short)hh;
        }
        sB[0][kstep][ntile][lane] = hi;
        sB[1][kstep][ntile][lane] = lo;
    }
    __syncthreads();

    const int lane  = tid & 63;
    const int wv_   = tid >> 6;
    const int row16 = lane & 15;
    const int kg    = lane >> 4;
    const int tb    = blockIdx.x - NPB;

    for (int wt = tb * 4 + wv_; wt < MTILES; wt += TBLKS * 4) {
        const int row = wt * 16 + row16;

        // A fragments: bf16-rounded only (no residual)
        short8 ah[2];
        #pragma unroll
        for (int s = 0; s < 2; s++) {
            const float* ap = nf + (size_t)row * 64 + s * 32 + kg * 8;
            #pragma unroll
            for (int r = 0; r < 8; r++)
                ah[s][r] = (short)f2bf(ap[r]);
        }

        #pragma unroll
        for (int nt = 0; nt < 8; nt++) {
            f32x4 acc = {0.f, 0.f, 0.f, 0.f};
            #pragma unroll
            for (int s = 0; s < 2; s++) {
                acc = __builtin_amdgcn_mfma_f32_16x16x32_bf16(ah[s], sB[0][s][nt][lane], acc, 0, 0, 0);
                acc = __builtin_amdgcn_mfma_f32_16x16x32_bf16(ah[s], sB[1][s][nt][lane], acc, 0, 0, 0);
            }
            const int col = nt * 16 + (lane & 15);
            const float b = sbias[col];
            unsigned short* outp = (col < 64) ? qbf : vbf;
            const int jj    = col & 63;
            const int rbase = wt * 16 + (lane >> 4) * 4;
            #pragma unroll
            for (int r = 0; r < 4; r++)
                outp[(size_t)(rbase + r) * 64 + jj] = f2bf(acc[r] + b);
        }
    }
}

// ---------------------------------------------------------------------------
// colbase: self-computes bucket totals (column sums of hist, coalesced,
// L2-resident) -> bbase scan; then scans its hist column across the NPB
// partition blocks. No gtotal buffer, no memset dependency.
// ---------------------------------------------------------------------------
__global__ __launch_bounds__(256) void colbase_kernel(
    const int* __restrict__ hist,
    int* __restrict__ bbase, int* __restrict__ colbase, int* __restrict__ offs)
{
    __shared__ int lds4[4];
    __shared__ int sb[256];
    const int bk = blockIdx.x;
    const int t  = threadIdx.x;

    int csum = 0;
    if (t < NBUCK) {
        #pragma unroll 8
        for (int b = 0; b < NPB; b++) csum += hist[b * NBUCK + t];
    }
    int gex = block_excl_scan_256(csum, lds4);
    sb[t] = gex;
    if (t == bk) bbase[bk] = gex;
    if (bk == 0 && t == NBUCK - 1) { bbase[NBUCK] = gex + csum; offs[NN] = NE; }
    __syncthreads();
    const int myBase = sb[bk];
    __syncthreads();

    int val = hist[t * NBUCK + bk];
    int ex  = block_excl_scan_256(val, lds4);
    colbase[t * NBUCK + bk] = myBase + ex;
}

__global__ __launch_bounds__(256) void partition_kernel(
    const int* __restrict__ esrc, const int* __restrict__ etgt,
    const int* __restrict__ colbase, unsigned int* __restrict__ packed)
{
    __shared__ int cur[NBUCK];
    const int blk = blockIdx.x;
    for (int i = threadIdx.x; i < NBUCK; i += 256)
        cur[i] = colbase[blk * NBUCK + i];
    __syncthreads();
    const int e0 = blk * CHUNK;
    const int e1 = min(e0 + CHUNK, NE);
    for (int e = e0 + threadIdx.x; e < e1; e += 256) {
        int t = etgt[e], s = esrc[e];
        int bk = t >> BSH;
        int pos = atomicAdd(&cur[bk], 1);
        packed[pos] = (unsigned)s | ((unsigned)(t & (NPBK - 1)) << 17);
    }
}

// 512 threads: 1 node-bin per thread, 8 waves/block for latency hiding
// (only NBUCK=196 blocks exist — parallelism lives inside the block).
__global__ __launch_bounds__(512) void bucket_csr_kernel(
    const unsigned int* __restrict__ packed, const int* __restrict__ bbase,
    int* __restrict__ offs, int* __restrict__ ssrc)
{
    __shared__ int cnt[NPBK];
    __shared__ int lds8[8];
    const int bk  = blockIdx.x;
    const int tid = threadIdx.x;
    const int s0 = bbase[bk], s1 = bbase[bk + 1];
    cnt[tid] = 0;
    __syncthreads();
    for (int e = s0 + tid; e < s1; e += 512)
        atomicAdd(&cnt[packed[e] >> 17], 1);
    __syncthreads();
    int a  = cnt[tid];
    int ex = block_excl_scan_512(a, lds8);
    const int node = (bk << BSH) + tid;
    const int g = s0 + ex;
    if (node < NN) offs[node] = g;
    __syncthreads();
    cnt[tid] = g;                        // becomes cursor
    __syncthreads();
    for (int e = s0 + tid; e < s1; e += 512) {
        unsigned p = packed[e];
        int pos = atomicAdd(&cnt[p >> 17], 1);
        ssrc[pos] = (int)(p & 0x1FFFFu);
    }
}

// ---------------------------------------------------------------------------
// Gather kernel v6 (UNCHANGED from R11 — at the random-gather memory wall):
// one wave per node; 8 lanes per edge (dwordx4 = 8 bf16 channels per lane),
// 8 edge slots, 2-stage rotation. Head logit reduce = ONE dpp add (lane^1).
// ---------------------------------------------------------------------------
__device__ __forceinline__ uint4 ldraw16(const unsigned short* __restrict__ vb,
                                         int src, int s8) {
    return *(const uint4*)((const char*)vb + ((size_t)src << 7) + s8 * 16);
}

__global__ __launch_bounds__(256) void gather_kernel(
    const unsigned short* __restrict__ qb, const unsigned short* __restrict__ vb,
    const float* __restrict__ ak,   // [16][4] row-major: ak[c*4+h]
    const int* __restrict__ offs, const int* __restrict__ ssrc,
    float* __restrict__ out)
{
    const int node = (blockIdx.x * 256 + threadIdx.x) >> 6;
    const int lane = threadIdx.x & 63;
    if (node >= NN) return;
    const int eslot = lane >> 3;     // edge slot 0..7
    const int s8    = lane & 7;      // channel octet 0..7
    const int h     = s8 >> 1;       // head 0..3

    const int start = offs[node];
    const int end   = offs[node + 1];

    if (start >= end) {
        if (lane < 8) {
            float4 z{0.f, 0.f, 0.f, 0.f};
            *(float4*)(out + (size_t)node * 64 + s8 * 8)     = z;
            *(float4*)(out + (size_t)node * 64 + s8 * 8 + 4) = z;
        }
        return;
    }
    const int end1 = end - 1;

    const float c6 = 0.6f * 1.44269504088896f;   // leaky + log2e folded
    const float c4 = 0.4f * 1.44269504088896f;
    float a6[8], a4[8];
    #pragma unroll
    for (int j = 0; j < 8; j++) {
        float k = ak[((s8 & 1) * 8 + j) * 4 + h];
        a6[j] = c6 * k;  a4[j] = c4 * k;
    }

    const uint4 qraw = *(const uint4*)((const char*)qb + ((size_t)node << 7) + s8 * 16);
    float q[8];
    q[0] = bflo(qraw.x); q[1] = bfhi(qraw.x);
    q[2] = bflo(qraw.y); q[3] = bfhi(qraw.y);
    q[4] = bflo(qraw.z); q[5] = bfhi(qraw.z);
    q[6] = bflo(qraw.w); q[7] = bfhi(qraw.w);

    int i0 = ssrc[min(start +     eslot, end1)];
    int i1 = ssrc[min(start + 8 + eslot, end1)];
    uint4 rr0 = ldraw16(vb, i0, s8);
    uint4 rr1 = ldraw16(vb, i1, s8);
    int mi0 = ssrc[min(start + 16 + eslot, end1)];
    int mi1 = ssrc[min(start + 24 + eslot, end1)];

    float acc[8] = {0.f, 0.f, 0.f, 0.f, 0.f, 0.f, 0.f, 0.f};
    float ws = 0.f;

    for (int p = start; p < end; p += 16) {
        {
            float v[8];
            v[0] = bflo(rr0.x); v[1] = bfhi(rr0.x);
            v[2] = bflo(rr0.y); v[3] = bfhi(rr0.y);
            v[4] = bflo(rr0.z); v[5] = bfhi(rr0.z);
            v[6] = bflo(rr0.w); v[7] = bfhi(rr0.w);
            rr0 = ldraw16(vb, mi0, s8);
            mi0 = ssrc[min(p + 32 + eslot, end1)];
            float x = 0.f;
            #pragma unroll
            for (int j = 0; j < 8; j++) {
                float f = q[j] + v[j];
                x = fmaf(f, a6[j], x);
                x = fmaf(fabsf(f), a4[j], x);
            }
            x = dpp_add<0xB1>(x);
            float w = (p + eslot < end) ? __builtin_amdgcn_exp2f(x) : 0.f;
            ws += w;
            #pragma unroll
            for (int j = 0; j < 8; j++) acc[j] = fmaf(w, v[j], acc[j]);
        }
        {
            float v[8];
            v[0] = bflo(rr1.x); v[1] = bfhi(rr1.x);
            v[2] = bflo(rr1.y); v[3] = bfhi(rr1.y);
            v[4] = bflo(rr1.z); v[5] = bfhi(rr1.z);
            v[6] = bflo(rr1.w); v[7] = bfhi(rr1.w);
            rr1 = ldraw16(vb, mi1, s8);
            mi1 = ssrc[min(p + 40 + eslot, end1)];
            float x = 0.f;
            #pragma unroll
            for (int j = 0; j < 8; j++) {
                float f = q[j] + v[j];
                x = fmaf(f, a6[j], x);
                x = fmaf(fabsf(f), a4[j], x);
            }
            x = dpp_add<0xB1>(x);
            float w = (p + 8 + eslot < end) ? __builtin_amdgcn_exp2f(x) : 0.f;
            ws += w;
            #pragma unroll
            for (int j = 0; j < 8; j++) acc[j] = fmaf(w, v[j], acc[j]);
        }
    }

    #pragma unroll
    for (int m = 8; m <= 32; m <<= 1) {
        #pragma unroll
        for (int j = 0; j < 8; j++) acc[j] += __shfl_xor(acc[j], m);
        ws += __shfl_xor(ws, m);
    }

    if (lane < 8) {
        float inv = (ws > 0.f) ? __frcp_rn(ws) : 1.0f;
        float r[8];
        #pragma unroll
        for (int j = 0; j < 8; j++) {
            float t = acc[j] * inv;
            r[j] = fmaxf(t, ALPHA * t);
        }
        *(float4*)(out + (size_t)node * 64 + s8 * 8)     = float4{r[0], r[1], r[2], r[3]};
        *(float4*)(out + (size_t)node * 64 + s8 * 8 + 4) = float4{r[4], r[5], r[6], r[7]};
    }
}

extern "C" void kernel_launch(void* const* d_in, const int* in_sizes, int n_in,
                              void* d_out, int out_size, void* d_ws, size_t ws_size,
                              hipStream_t stream) {
    const float* nf   = (const float*)d_in[0];
    const float* Wq   = (const float*)d_in[1];
    const float* bq   = (const float*)d_in[2];
    const float* Wv   = (const float*)d_in[3];
    const float* bv   = (const float*)d_in[4];
    const float* ak   = (const float*)d_in[5];
    const int*   esrc = (const int*)d_in[6];
    const int*   etgt = (const int*)d_in[7];
    float* out = (float*)d_out;

    // workspace layout:
    //   qbf:     NN*64      u16  (12.8 MB)
    //   vbf:     NN*64      u16  (12.8 MB)
    //   offs:    NN+1       i32
    //   ssrc:    NE         i32  (6.4 MB)
    //   packed:  NE         u32  (6.4 MB)
    //   hist:    NPB*NBUCK  i32  (200 KB)
    //   colbase: NPB*NBUCK  i32  (200 KB)
    //   bbase:   NBUCK+1    i32
    unsigned short* qbf     = (unsigned short*)d_ws;
    unsigned short* vbf     = qbf + (size_t)NN * 64;
    int*            offs    = (int*)(vbf + (size_t)NN * 64);
    int*            ssrc    = offs + (NN + 1);
    unsigned int*   packed  = (unsigned int*)(ssrc + NE);
    int*            hist    = (int*)(packed + NE);
    int*            colbase = hist + NPB * NBUCK;
    int*            bbase   = colbase + NPB * NBUCK;

    fused_tc_kernel<<<NPB + TBLKS, 256, 0, stream>>>(nf, Wq, bq, Wv, bv, qbf, vbf,
                                                     etgt, hist);
    colbase_kernel<<<NBUCK, 256, 0, stream>>>(hist, bbase, colbase, offs);
    partition_kernel<<<NPB, 256, 0, stream>>>(esrc, etgt, colbase, packed);
    bucket_csr_kernel<<<NBUCK, 512, 0, stream>>>(packed, bbase, offs, ssrc);
    gather_kernel<<<(NN * 64 + 255) / 256, 256, 0, stream>>>(qbf, vbf, ak, offs, ssrc, out);
}

// Round 13
// 105.292 us; speedup vs baseline: 1.2621x; 1.0745x over previous
//
#include <hip/hip_runtime.h>

#define NN 100000
#define NE 1600000
#define ALPHA 0.2f

#define BSH   9                          // 512 nodes per bucket
#define NPBK  512                        // nodes per bucket
#define NBUCK ((NN + NPBK - 1) / NPBK)   // 196 buckets
#define NPB   256                        // partition / count blocks
#define CHUNK ((NE + NPB - 1) / NPB)     // 6250 edges per block

#define MTILES (NN / 16)                 // 6250 (NN % 16 == 0)

// transform slices across the 4 CSR-stage kernels (proportional to stage time)
#define TB1 0
#define N1  290      // K1: tiles 0..1159        (4 tiles/block, 256 thr)
#define TB2 1160
#define N2  145      // K2: tiles 1160..1739
#define TB3 1740
#define N3  638      // K3: tiles 1740..4291
#define TB4 4292
#define N4  245      // K4: tiles 4292..6251     (8 tiles/block, 512 thr; guard)

typedef __attribute__((ext_vector_type(8))) short  short8;
typedef __attribute__((ext_vector_type(4))) float  f32x4;

// ---------------- bf16 helpers (RNE pack, cheap unpack) ---------------------
__device__ __forceinline__ unsigned short f2bf(float f) {
    unsigned int u = __builtin_bit_cast(unsigned int, f);
    u += 0x7FFFu + ((u >> 16) & 1u);
    return (unsigned short)(u >> 16);
}
__device__ __forceinline__ float bf2fs(unsigned short u) {
    return __builtin_bit_cast(float, (unsigned int)u << 16);
}
__device__ __forceinline__ float bflo(unsigned int u) {
    return __builtin_bit_cast(float, u << 16);
}
__device__ __forceinline__ float bfhi(unsigned int u) {
    return __builtin_bit_cast(float, u & 0xFFFF0000u);
}

// ---------------- DPP adds (all VALU, no DS pipe) ---------------------------
template<int CTRL>
__device__ __forceinline__ float dpp_add(float x) {
    int y = __builtin_amdgcn_update_dpp(0, __builtin_bit_cast(int, x),
                                        CTRL, 0xF, 0xF, true);
    return x + __builtin_bit_cast(float, y);
}

// ---------------- block exclusive scans -------------------------------------
__device__ __forceinline__ int block_excl_scan_256(int val, int* lds4) {
    const int lane = threadIdx.x & 63;
    const int wid  = threadIdx.x >> 6;
    int incl = val;
    #pragma unroll
    for (int off = 1; off < 64; off <<= 1) {
        int t = __shfl_up(incl, off);
        if (lane >= off) incl += t;
    }
    if (lane == 63) lds4[wid] = incl;
    __syncthreads();
    int wbase = 0;
    #pragma unroll
    for (int w = 0; w < 4; w++) if (w < wid) wbase += lds4[w];
    __syncthreads();
    return wbase + incl - val;
}

__device__ __forceinline__ int block_excl_scan_512(int val, int* lds8) {
    const int lane = threadIdx.x & 63;
    const int wid  = threadIdx.x >> 6;   // 0..7
    int incl = val;
    #pragma unroll
    for (int off = 1; off < 64; off <<= 1) {
        int t = __shfl_up(incl, off);
        if (lane >= off) incl += t;
    }
    if (lane == 63) lds8[wid] = incl;
    __syncthreads();
    int wbase = 0;
    #pragma unroll
    for (int w = 0; w < 8; w++) if (w < wid) wbase += lds8[w];
    __syncthreads();
    return wbase + incl - val;
}

// ---------------------------------------------------------------------------
// Transform helpers (MFMA, acc = A_bf16 · (B_hi + B_lo); B split once per
// block into LDS).  C/D layout (HW-verified): col=lane&15, row=(lane>>4)*4+reg.
// ---------------------------------------------------------------------------
__device__ __forceinline__ void transform_prep(
    const float* __restrict__ Wq, const float* __restrict__ bq,
    const float* __restrict__ Wv, const float* __restrict__ bv,
    short8 (*sB)[2][8][64], float* sbias, int tid, int nthr)
{
    if (tid < 64)       sbias[tid] = bq[tid];
    else if (tid < 128) sbias[tid] = bv[tid - 64];
    for (int slot = tid; slot < 2 * 8 * 64; slot += nthr) {
        const int lane  = slot & 63;
        const int ntile = (slot >> 6) & 7;
        const int kstep = slot >> 9;
        const int j     = ntile * 16 + (lane & 15);
        const int kbase = kstep * 32 + (lane >> 4) * 8;
        const float* W  = (j < 64) ? Wq : Wv;
        const int jj    = j & 63;
        short8 hi, lo;
        #pragma unroll
        for (int r = 0; r < 8; r++) {
            float w = W[(kbase + r) * 64 + jj];
            unsigned short hh = f2bf(w);
            lo[r] = (short)f2bf(w - bf2fs(hh));
            hi[r] = (short)hh;
        }
        sB[0][kstep][ntile][lane] = hi;
        sB[1][kstep][ntile][lane] = lo;
    }
}

__device__ __forceinline__ void transform_tile(
    const float* __restrict__ nf,
    unsigned short* __restrict__ qbf, unsigned short* __restrict__ vbf,
    short8 (*sB)[2][8][64], const float* sbias, int wt, int lane)
{
    const int row = wt * 16 + (lane & 15);
    short8 ah[2];
    #pragma unroll
    for (int s = 0; s < 2; s++) {
        const float* ap = nf + (size_t)row * 64 + s * 32 + (lane >> 4) * 8;
        #pragma unroll
        for (int r = 0; r < 8; r++)
            ah[s][r] = (short)f2bf(ap[r]);
    }
    #pragma unroll
    for (int nt = 0; nt < 8; nt++) {
        f32x4 acc = {0.f, 0.f, 0.f, 0.f};
        #pragma unroll
        for (int s = 0; s < 2; s++) {
            acc = __builtin_amdgcn_mfma_f32_16x16x32_bf16(ah[s], sB[0][s][nt][lane], acc, 0, 0, 0);
            acc = __builtin_amdgcn_mfma_f32_16x16x32_bf16(ah[s], sB[1][s][nt][lane], acc, 0, 0, 0);
        }
        const int col = nt * 16 + (lane & 15);
        const float b = sbias[col];
        unsigned short* outp = (col < 64) ? qbf : vbf;
        const int jj    = col & 63;
        const int rbase = wt * 16 + (lane >> 4) * 4;
        #pragma unroll
        for (int r = 0; r < 4; r++)
            outp[(size_t)(rbase + r) * 64 + jj] = f2bf(acc[r] + b);
    }
}

// ---------------------------------------------------------------------------
// K1: blocks 0..NPB-1 bucket histogram; rest transform tiles TB1..
// ---------------------------------------------------------------------------
__global__ __launch_bounds__(256) void k1_hist_tf(
    const float* __restrict__ nf, const float* __restrict__ Wq, const float* __restrict__ bq,
    const float* __restrict__ Wv, const float* __restrict__ bv,
    unsigned short* __restrict__ qbf, unsigned short* __restrict__ vbf,
    const int* __restrict__ etgt, int* __restrict__ hist)
{
    __shared__ short8 sB[2][2][8][64];
    __shared__ float  sbias[128];
    __shared__ int    h[NBUCK];
    const int tid = threadIdx.x;

    if (blockIdx.x < NPB) {
        const int blk = blockIdx.x;
        for (int i = tid; i < NBUCK; i += 256) h[i] = 0;
        __syncthreads();
        const int e0 = blk * CHUNK;
        const int e1 = min(e0 + CHUNK, NE);
        for (int e = e0 + tid; e < e1; e += 256)
            atomicAdd(&h[etgt[e] >> BSH], 1);
        __syncthreads();
        for (int i = tid; i < NBUCK; i += 256)
            hist[blk * NBUCK + i] = h[i];
        return;
    }

    transform_prep(Wq, bq, Wv, bv, sB, sbias, tid, 256);
    __syncthreads();
    const int wt = TB1 + ((int)blockIdx.x - NPB) * 4 + (tid >> 6);
    if (wt < MTILES) transform_tile(nf, qbf, vbf, sB, sbias, wt, tid & 63);
}

// ---------------------------------------------------------------------------
// K2: blocks 0..NBUCK-1 colbase (self-computes bucket totals); rest transform.
// ---------------------------------------------------------------------------
__global__ __launch_bounds__(256) void k2_colbase_tf(
    const float* __restrict__ nf, const float* __restrict__ Wq, const float* __restrict__ bq,
    const float* __restrict__ Wv, const float* __restrict__ bv,
    unsigned short* __restrict__ qbf, unsigned short* __restrict__ vbf,
    const int* __restrict__ hist,
    int* __restrict__ bbase, int* __restrict__ colbase, int* __restrict__ offs)
{
    __shared__ short8 sB[2][2][8][64];
    __shared__ float  sbias[128];
    __shared__ int lds4[4];
    __shared__ int sb[256];
    const int t = threadIdx.x;

    if (blockIdx.x < NBUCK) {
        const int bk = blockIdx.x;
        int csum = 0;
        if (t < NBUCK) {
            #pragma unroll 8
            for (int b = 0; b < NPB; b++) csum += hist[b * NBUCK + t];
        }
        int gex = block_excl_scan_256(csum, lds4);
        sb[t] = gex;
        if (t == bk) bbase[bk] = gex;
        if (bk == 0 && t == NBUCK - 1) { bbase[NBUCK] = gex + csum; offs[NN] = NE; }
        __syncthreads();
        const int myBase = sb[bk];
        __syncthreads();

        int val = hist[t * NBUCK + bk];
        int ex  = block_excl_scan_256(val, lds4);
        colbase[t * NBUCK + bk] = myBase + ex;
        return;
    }

    transform_prep(Wq, bq, Wv, bv, sB, sbias, t, 256);
    __syncthreads();
    const int wt = TB2 + ((int)blockIdx.x - NBUCK) * 4 + (t >> 6);
    if (wt < MTILES) transform_tile(nf, qbf, vbf, sB, sbias, wt, t & 63);
}

// ---------------------------------------------------------------------------
// K3: blocks 0..NPB-1 partition; rest transform.
// ---------------------------------------------------------------------------
__global__ __launch_bounds__(256) void k3_partition_tf(
    const float* __restrict__ nf, const float* __restrict__ Wq, const float* __restrict__ bq,
    const float* __restrict__ Wv, const float* __restrict__ bv,
    unsigned short* __restrict__ qbf, unsigned short* __restrict__ vbf,
    const int* __restrict__ esrc, const int* __restrict__ etgt,
    const int* __restrict__ colbase, unsigned int* __restrict__ packed)
{
    __shared__ short8 sB[2][2][8][64];
    __shared__ float  sbias[128];
    __shared__ int cur[NBUCK];
    const int tid = threadIdx.x;

    if (blockIdx.x < NPB) {
        const int blk = blockIdx.x;
        for (int i = tid; i < NBUCK; i += 256)
            cur[i] = colbase[blk * NBUCK + i];
        __syncthreads();
        const int e0 = blk * CHUNK;
        const int e1 = min(e0 + CHUNK, NE);
        for (int e = e0 + tid; e < e1; e += 256) {
            int t = etgt[e], s = esrc[e];
            int bk = t >> BSH;
            int pos = atomicAdd(&cur[bk], 1);
            packed[pos] = (unsigned)s | ((unsigned)(t & (NPBK - 1)) << 17);
        }
        return;
    }

    transform_prep(Wq, bq, Wv, bv, sB, sbias, tid, 256);
    __syncthreads();
    const int wt = TB3 + ((int)blockIdx.x - NPB) * 4 + (tid >> 6);
    if (wt < MTILES) transform_tile(nf, qbf, vbf, sB, sbias, wt, tid & 63);
}

// ---------------------------------------------------------------------------
// K4 (512 threads): blocks 0..NBUCK-1 bucket counting-sort -> offs+ssrc;
// rest transform (8 tiles/block).
// ---------------------------------------------------------------------------
__global__ __launch_bounds__(512) void k4_csr_tf(
    const float* __restrict__ nf, const float* __restrict__ Wq, const float* __restrict__ bq,
    const float* __restrict__ Wv, const float* __restrict__ bv,
    unsigned short* __restrict__ qbf, unsigned short* __restrict__ vbf,
    const unsigned int* __restrict__ packed, const int* __restrict__ bbase,
    int* __restrict__ offs, int* __restrict__ ssrc)
{
    __shared__ short8 sB[2][2][8][64];
    __shared__ float  sbias[128];
    __shared__ int cnt[NPBK];
    __shared__ int lds8[8];
    const int tid = threadIdx.x;

    if (blockIdx.x < NBUCK) {
        const int bk = blockIdx.x;
        const int s0 = bbase[bk], s1 = bbase[bk + 1];
        cnt[tid] = 0;
        __syncthreads();
        for (int e = s0 + tid; e < s1; e += 512)
            atomicAdd(&cnt[packed[e] >> 17], 1);
        __syncthreads();
        int a  = cnt[tid];
        int ex = block_excl_scan_512(a, lds8);
        const int node = (bk << BSH) + tid;
        const int g = s0 + ex;
        if (node < NN) offs[node] = g;
        __syncthreads();
        cnt[tid] = g;                        // becomes cursor
        __syncthreads();
        for (int e = s0 + tid; e < s1; e += 512) {
            unsigned p = packed[e];
            int pos = atomicAdd(&cnt[p >> 17], 1);
            ssrc[pos] = (int)(p & 0x1FFFFu);
        }
        return;
    }

    transform_prep(Wq, bq, Wv, bv, sB, sbias, tid, 512);
    __syncthreads();
    const int wt = TB4 + ((int)blockIdx.x - NBUCK) * 8 + (tid >> 6);
    if (wt < MTILES) transform_tile(nf, qbf, vbf, sB, sbias, wt, tid & 63);
}

// ---------------------------------------------------------------------------
// Gather kernel (UNCHANGED — at the random-gather memory wall):
// one wave per node; 8 lanes per edge (dwordx4 = 8 bf16 channels per lane),
// 8 edge slots, 2-stage rotation. Head logit reduce = ONE dpp add (lane^1).
// ---------------------------------------------------------------------------
__device__ __forceinline__ uint4 ldraw16(const unsigned short* __restrict__ vb,
                                         int src, int s8) {
    return *(const uint4*)((const char*)vb + ((size_t)src << 7) + s8 * 16);
}

__global__ __launch_bounds__(256) void gather_kernel(
    const unsigned short* __restrict__ qb, const unsigned short* __restrict__ vb,
    const float* __restrict__ ak,   // [16][4] row-major: ak[c*4+h]
    const int* __restrict__ offs, const int* __restrict__ ssrc,
    float* __restrict__ out)
{
    const int node = (blockIdx.x * 256 + threadIdx.x) >> 6;
    const int lane = threadIdx.x & 63;
    if (node >= NN) return;
    const int eslot = lane >> 3;     // edge slot 0..7
    const int s8    = lane & 7;      // channel octet 0..7
    const int h     = s8 >> 1;       // head 0..3

    const int start = offs[node];
    const int end   = offs[node + 1];

    if (start >= end) {
        if (lane < 8) {
            float4 z{0.f, 0.f, 0.f, 0.f};
            *(float4*)(out + (size_t)node * 64 + s8 * 8)     = z;
            *(float4*)(out + (size_t)node * 64 + s8 * 8 + 4) = z;
        }
        return;
    }
    const int end1 = end - 1;

    const float c6 = 0.6f * 1.44269504088896f;   // leaky + log2e folded
    const float c4 = 0.4f * 1.44269504088896f;
    float a6[8], a4[8];
    #pragma unroll
    for (int j = 0; j < 8; j++) {
        float k = ak[((s8 & 1) * 8 + j) * 4 + h];
        a6[j] = c6 * k;  a4[j] = c4 * k;
    }

    const uint4 qraw = *(const uint4*)((const char*)qb + ((size_t)node << 7) + s8 * 16);
    float q[8];
    q[0] = bflo(qraw.x); q[1] = bfhi(qraw.x);
    q[2] = bflo(qraw.y); q[3] = bfhi(qraw.y);
    q[4] = bflo(qraw.z); q[5] = bfhi(qraw.z);
    q[6] = bflo(qraw.w); q[7] = bfhi(qraw.w);

    int i0 = ssrc[min(start +     eslot, end1)];
    int i1 = ssrc[min(start + 8 + eslot, end1)];
    uint4 rr0 = ldraw16(vb, i0, s8);
    uint4 rr1 = ldraw16(vb, i1, s8);
    int mi0 = ssrc[min(start + 16 + eslot, end1)];
    int mi1 = ssrc[min(start + 24 + eslot, end1)];

    float acc[8] = {0.f, 0.f, 0.f, 0.f, 0.f, 0.f, 0.f, 0.f};
    float ws = 0.f;

    for (int p = start; p < end; p += 16) {
        {
            float v[8];
            v[0] = bflo(rr0.x); v[1] = bfhi(rr0.x);
            v[2] = bflo(rr0.y); v[3] = bfhi(rr0.y);
            v[4] = bflo(rr0.z); v[5] = bfhi(rr0.z);
            v[6] = bflo(rr0.w); v[7] = bfhi(rr0.w);
            rr0 = ldraw16(vb, mi0, s8);
            mi0 = ssrc[min(p + 32 + eslot, end1)];
            float x = 0.f;
            #pragma unroll
            for (int j = 0; j < 8; j++) {
                float f = q[j] + v[j];
                x = fmaf(f, a6[j], x);
                x = fmaf(fabsf(f), a4[j], x);
            }
            x = dpp_add<0xB1>(x);
            float w = (p + eslot < end) ? __builtin_amdgcn_exp2f(x) : 0.f;
            ws += w;
            #pragma unroll
            for (int j = 0; j < 8; j++) acc[j] = fmaf(w, v[j], acc[j]);
        }
        {
            float v[8];
            v[0] = bflo(rr1.x); v[1] = bfhi(rr1.x);
            v[2] = bflo(rr1.y); v[3] = bfhi(rr1.y);
            v[4] = bflo(rr1.z); v[5] = bfhi(rr1.z);
            v[6] = bflo(rr1.w); v[7] = bfhi(rr1.w);
            rr1 = ldraw16(vb, mi1, s8);
            mi1 = ssrc[min(p + 40 + eslot, end1)];
            float x = 0.f;
            #pragma unroll
            for (int j = 0; j < 8; j++) {
                float f = q[j] + v[j];
                x = fmaf(f, a6[j], x);
                x = fmaf(fabsf(f), a4[j], x);
            }
            x = dpp_add<0xB1>(x);
            float w = (p + 8 + eslot < end) ? __builtin_amdgcn_exp2f(x) : 0.f;
            ws += w;
            #pragma unroll
            for (int j = 0; j < 8; j++) acc[j] = fmaf(w, v[j], acc[j]);
        }
    }

    #pragma unroll
    for (int m = 8; m <= 32; m <<= 1) {
        #pragma unroll
        for (int j = 0; j < 8; j++) acc[j] += __shfl_xor(acc[j], m);
        ws += __shfl_xor(ws, m);
    }

    if (lane < 8) {
        float inv = (ws > 0.f) ? __frcp_rn(ws) : 1.0f;
        float r[8];
        #pragma unroll
        for (int j = 0; j < 8; j++) {
            float t = acc[j] * inv;
            r[j] = fmaxf(t, ALPHA * t);
        }
        *(float4*)(out + (size_t)node * 64 + s8 * 8)     = float4{r[0], r[1], r[2], r[3]};
        *(float4*)(out + (size_t)node * 64 + s8 * 8 + 4) = float4{r[4], r[5], r[6], r[7]};
    }
}

extern "C" void kernel_launch(void* const* d_in, const int* in_sizes, int n_in,
                              void* d_out, int out_size, void* d_ws, size_t ws_size,
                              hipStream_t stream) {
    const float* nf   = (const float*)d_in[0];
    const float* Wq   = (const float*)d_in[1];
    const float* bq   = (const float*)d_in[2];
    const float* Wv   = (const float*)d_in[3];
    const float* bv   = (const float*)d_in[4];
    const float* ak   = (const float*)d_in[5];
    const int*   esrc = (const int*)d_in[6];
    const int*   etgt = (const int*)d_in[7];
    float* out = (float*)d_out;

    // workspace layout:
    //   qbf:     NN*64      u16  (12.8 MB)
    //   vbf:     NN*64      u16  (12.8 MB)
    //   offs:    NN+1       i32
    //   ssrc:    NE         i32  (6.4 MB)
    //   packed:  NE         u32  (6.4 MB)
    //   hist:    NPB*NBUCK  i32  (200 KB)
    //   colbase: NPB*NBUCK  i32  (200 KB)
    //   bbase:   NBUCK+1    i32
    unsigned short* qbf     = (unsigned short*)d_ws;
    unsigned short* vbf     = qbf + (size_t)NN * 64;
    int*            offs    = (int*)(vbf + (size_t)NN * 64);
    int*            ssrc    = offs + (NN + 1);
    unsigned int*   packed  = (unsigned int*)(ssrc + NE);
    int*            hist    = (int*)(packed + NE);
    int*            colbase = hist + NPB * NBUCK;
    int*            bbase   = colbase + NPB * NBUCK;

    k1_hist_tf<<<NPB + N1, 256, 0, stream>>>(nf, Wq, bq, Wv, bv, qbf, vbf, etgt, hist);
    k2_colbase_tf<<<NBUCK + N2, 256, 0, stream>>>(nf, Wq, bq, Wv, bv, qbf, vbf,
                                                  hist, bbase, colbase, offs);
    k3_partition_tf<<<NPB + N3, 256, 0, stream>>>(nf, Wq, bq, Wv, bv, qbf, vbf,
                                                  esrc, etgt, colbase, packed);
    k4_csr_tf<<<NBUCK + N4, 512, 0, stream>>>(nf, Wq, bq, Wv, bv, qbf, vbf,
                                              packed, bbase, offs, ssrc);
    gather_kernel<<<(NN * 64 + 255) / 256, 256, 0, stream>>>(qbf, vbf, ak, offs, ssrc, out);
}